// Round 2
// baseline (2456.443 us; speedup 1.0000x reference)
//
#include <hip/hip_runtime.h>

#define NN 50000
#define EE 250000
#define HD 128

// ---------------- CSR build ----------------
__global__ void hist_kernel(const int* __restrict__ row, int* __restrict__ cnt) {
    int e = blockIdx.x * blockDim.x + threadIdx.x;
    if (e < EE) atomicAdd(&cnt[row[e]], 1);
}

__global__ __launch_bounds__(1024) void scan_kernel(const int* __restrict__ cnt,
                                                    int* __restrict__ rp) {
    __shared__ int s[1024];
    int tid = threadIdx.x;
    int c0 = 0;
    for (int base = 0; base < NN; base += 8192) {
        int v[8];
        int sum = 0;
        int i0 = base + tid * 8;
#pragma unroll
        for (int j = 0; j < 8; ++j) {
            int i = i0 + j;
            v[j] = (i < NN) ? cnt[i] : 0;
            sum += v[j];
        }
        s[tid] = sum;
        __syncthreads();
        for (int off = 1; off < 1024; off <<= 1) {
            int t = (tid >= off) ? s[tid - off] : 0;
            __syncthreads();
            s[tid] += t;
            __syncthreads();
        }
        int excl = c0 + s[tid] - sum;
#pragma unroll
        for (int j = 0; j < 8; ++j) {
            int i = i0 + j;
            if (i < NN) rp[i] = excl;
            excl += v[j];
        }
        int tot = s[1023];
        __syncthreads();
        c0 += tot;
    }
    if (tid == 0) rp[NN] = c0;
}

__global__ void scatter_kernel(const int* __restrict__ row, const int* __restrict__ col,
                               const float* __restrict__ val, const int* __restrict__ rp,
                               int* __restrict__ cur, int* __restrict__ cols_s,
                               float* __restrict__ vals_s) {
    int e = blockIdx.x * blockDim.x + threadIdx.x;
    if (e >= EE) return;
    int r = row[e];
    int p = atomicAdd(&cur[r], 1);
    int d = rp[r] + p;
    cols_s[d] = col[e];
    vals_s[d] = val[e];
}

// ---------------- SpMM (CSR) + ReLU (+ l2norm) ----------------
// one wave per output row; lane owns 2 of the 128 columns
__global__ __launch_bounds__(256) void spmm_kernel(const int* __restrict__ rp,
                                                   const int* __restrict__ cols,
                                                   const float* __restrict__ vals,
                                                   const float* __restrict__ xin,
                                                   float* __restrict__ xout, int do_norm) {
    int w = (blockIdx.x * 256 + threadIdx.x) >> 6;
    int lane = threadIdx.x & 63;
    if (w >= NN) return;
    int beg = rp[w], end = rp[w + 1];
    float ax = 0.f, ay = 0.f;
    for (int e = beg; e < end; ++e) {
        int c = cols[e];
        float v = vals[e];
        const float2 xr = *(const float2*)(xin + (size_t)c * HD + lane * 2);
        ax = fmaf(v, xr.x, ax);
        ay = fmaf(v, xr.y, ay);
    }
    ax = fmaxf(ax, 0.f);
    ay = fmaxf(ay, 0.f);
    if (do_norm) {
        float ss = ax * ax + ay * ay;
#pragma unroll
        for (int off = 32; off > 0; off >>= 1) ss += __shfl_xor(ss, off, 64);
        float scale = 1.f / fmaxf(sqrtf(ss), 1e-12f);
        ax *= scale;
        ay *= scale;
    }
    float2 o;
    o.x = ax;
    o.y = ay;
    *(float2*)(xout + (size_t)w * HD + lane * 2) = o;
}

// ---------------- dense GEMM: y = x @ W (W is 128x128) ----------------
// 64-row tile; X^T staged in LDS (pad to 68 to keep 16B alignment + bank spread)
__global__ __launch_bounds__(256) void gemm128_kernel(const float* __restrict__ x,
                                                      const float* __restrict__ W,
                                                      float* __restrict__ y) {
    __shared__ float Xt[HD][68];
    int tile = blockIdx.x * 64;
    int tid = threadIdx.x;
#pragma unroll
    for (int it = 0; it < 8; ++it) {
        int idx = it * 256 + tid;   // 0..2047 float4 slots
        int r = idx >> 5;           // 64 rows x 32 float4/row
        int k4 = (idx & 31) * 4;
        float4 xv = make_float4(0.f, 0.f, 0.f, 0.f);
        if (tile + r < NN) xv = *(const float4*)(x + (size_t)(tile + r) * HD + k4);
        Xt[k4 + 0][r] = xv.x;
        Xt[k4 + 1][r] = xv.y;
        Xt[k4 + 2][r] = xv.z;
        Xt[k4 + 3][r] = xv.w;
    }
    __syncthreads();
    int cg = tid & 31, rg = tid >> 5;
    int c0 = cg * 4, r0 = rg * 8;
    float acc[8][4] = {};
    for (int k = 0; k < HD; ++k) {
        float4 wv = *(const float4*)(W + k * HD + c0);
        float4 xa = *(const float4*)(&Xt[k][r0]);
        float4 xb = *(const float4*)(&Xt[k][r0 + 4]);
        float xs[8] = {xa.x, xa.y, xa.z, xa.w, xb.x, xb.y, xb.z, xb.w};
        float wr[4] = {wv.x, wv.y, wv.z, wv.w};
#pragma unroll
        for (int i = 0; i < 8; ++i)
#pragma unroll
            for (int j = 0; j < 4; ++j) acc[i][j] = fmaf(xs[i], wr[j], acc[i][j]);
    }
#pragma unroll
    for (int i = 0; i < 8; ++i) {
        int r = tile + r0 + i;
        if (r < NN) {
            float4 o;
            o.x = acc[i][0];
            o.y = acc[i][1];
            o.z = acc[i][2];
            o.w = acc[i][3];
            *(float4*)(y + (size_t)r * HD + c0) = o;
        }
    }
}

// ---------------- fused MLP: score[n] += mlp(x[n]) ----------------
// 32-node tile; X^T (18KB) and H1^T (36KB) live in LDS; layer3 dot fused
// into layer2 epilogue with a 32-lane shuffle reduction.
__global__ __launch_bounds__(256) void mlp_kernel(const float* __restrict__ x,
                                                  const float* __restrict__ L1w,
                                                  const float* __restrict__ L1b,
                                                  const float* __restrict__ L2w,
                                                  const float* __restrict__ L2b,
                                                  const float* __restrict__ L3w,
                                                  const float* __restrict__ L3b,
                                                  float* __restrict__ score) {
    __shared__ float Xt[HD][36];
    __shared__ float H1t[256][36];
    __shared__ float red[32];
    int tile = blockIdx.x * 32;
    int tid = threadIdx.x;
#pragma unroll
    for (int it = 0; it < 4; ++it) {
        int idx = it * 256 + tid;   // 0..1023 float4 slots
        int n = idx >> 5;           // 32 nodes x 32 float4/node
        int k4 = (idx & 31) * 4;
        float4 xv = make_float4(0.f, 0.f, 0.f, 0.f);
        if (tile + n < NN) xv = *(const float4*)(x + (size_t)(tile + n) * HD + k4);
        Xt[k4 + 0][n] = xv.x;
        Xt[k4 + 1][n] = xv.y;
        Xt[k4 + 2][n] = xv.z;
        Xt[k4 + 3][n] = xv.w;
    }
    __syncthreads();
    int cg = tid & 31, rg = tid >> 5;
    int c0 = cg * 8, r0 = rg * 4;
    // ---- layer 1: h1 = relu(x @ L1w + b1), stored transposed in LDS ----
    {
        float acc[4][8] = {};
        for (int k = 0; k < HD; ++k) {
            float4 xv = *(const float4*)(&Xt[k][r0]);
            float4 wa = *(const float4*)(L1w + k * 256 + c0);
            float4 wb = *(const float4*)(L1w + k * 256 + c0 + 4);
            float xs[4] = {xv.x, xv.y, xv.z, xv.w};
            float wr[8] = {wa.x, wa.y, wa.z, wa.w, wb.x, wb.y, wb.z, wb.w};
#pragma unroll
            for (int i = 0; i < 4; ++i)
#pragma unroll
                for (int j = 0; j < 8; ++j) acc[i][j] = fmaf(xs[i], wr[j], acc[i][j]);
        }
#pragma unroll
        for (int j = 0; j < 8; ++j) {
            float b = L1b[c0 + j];
#pragma unroll
            for (int i = 0; i < 4; ++i) H1t[c0 + j][r0 + i] = fmaxf(acc[i][j] + b, 0.f);
        }
    }
    __syncthreads();
    // ---- layer 2 + layer 3: s[n] = sum_c relu(h1 @ L2w + b2)[c] * L3w[c] ----
    {
        float acc[4][8] = {};
        for (int k = 0; k < 256; ++k) {
            float4 xv = *(const float4*)(&H1t[k][r0]);
            float4 wa = *(const float4*)(L2w + k * 256 + c0);
            float4 wb = *(const float4*)(L2w + k * 256 + c0 + 4);
            float xs[4] = {xv.x, xv.y, xv.z, xv.w};
            float wr[8] = {wa.x, wa.y, wa.z, wa.w, wb.x, wb.y, wb.z, wb.w};
#pragma unroll
            for (int i = 0; i < 4; ++i)
#pragma unroll
                for (int j = 0; j < 8; ++j) acc[i][j] = fmaf(xs[i], wr[j], acc[i][j]);
        }
        float part[4] = {0.f, 0.f, 0.f, 0.f};
#pragma unroll
        for (int j = 0; j < 8; ++j) {
            float b = L2b[c0 + j], w3 = L3w[c0 + j];
#pragma unroll
            for (int i = 0; i < 4; ++i) part[i] = fmaf(fmaxf(acc[i][j] + b, 0.f), w3, part[i]);
        }
#pragma unroll
        for (int off = 16; off > 0; off >>= 1)
#pragma unroll
            for (int i = 0; i < 4; ++i) part[i] += __shfl_xor(part[i], off, 64);
        if ((tid & 31) == 0) {
#pragma unroll
            for (int i = 0; i < 4; ++i) red[r0 + i] = part[i];
        }
    }
    __syncthreads();
    if (tid < 32) {
        int g = tile + tid;
        if (g < NN) score[g] += red[tid] + L3b[0];
    }
}

__global__ void final_kernel(const float* __restrict__ s1, const float* __restrict__ s2,
                             float* __restrict__ out) {
    int i = blockIdx.x * blockDim.x + threadIdx.x;
    if (i < NN) out[i] = s1[i] * s2[i];
}

extern "C" void kernel_launch(void* const* d_in, const int* in_sizes, int n_in,
                              void* d_out, int out_size, void* d_ws, size_t ws_size,
                              hipStream_t stream) {
    const int* row1 = (const int*)d_in[0];
    const int* col1 = (const int*)d_in[1];
    const float* val1 = (const float*)d_in[2];
    const int* row2 = (const int*)d_in[3];
    const int* col2 = (const int*)d_in[4];
    const float* val2 = (const float*)d_in[5];
    const float* W0 = (const float*)d_in[6];
    const float* Wg[4] = {(const float*)d_in[7], (const float*)d_in[8], (const float*)d_in[9],
                          (const float*)d_in[10]};
    const float* L1w = (const float*)d_in[11];
    const float* L1b = (const float*)d_in[12];
    const float* L2w = (const float*)d_in[13];
    const float* L2b = (const float*)d_in[14];
    const float* L3w = (const float*)d_in[15];
    const float* L3b = (const float*)d_in[16];
    float* out = (float*)d_out;

    char* ws = (char*)d_ws;
    size_t off = 0;
    auto alloc = [&](size_t bytes) {
        void* p = ws + off;
        off = (off + bytes + 255) & ~(size_t)255;
        return p;
    };
    int* rp1 = (int*)alloc((NN + 1) * 4);
    int* cols1 = (int*)alloc(EE * 4);
    float* vals1 = (float*)alloc(EE * 4);
    int* rp2 = (int*)alloc((NN + 1) * 4);
    int* cols2 = (int*)alloc(EE * 4);
    float* vals2 = (float*)alloc(EE * 4);
    int* cnt = (int*)alloc(NN * 4);
    int* cur = (int*)alloc(NN * 4);
    float* xbuf = (float*)alloc((size_t)NN * HD * 4);
    float* ybuf = (float*)alloc((size_t)NN * HD * 4);
    float* s1 = (float*)alloc(NN * 4);
    float* s2 = (float*)alloc(NN * 4);

    // ---- CSR build, graph 1 ----
    hipMemsetAsync(cnt, 0, NN * 4, stream);
    hipMemsetAsync(cur, 0, NN * 4, stream);
    hist_kernel<<<(EE + 255) / 256, 256, 0, stream>>>(row1, cnt);
    scan_kernel<<<1, 1024, 0, stream>>>(cnt, rp1);
    scatter_kernel<<<(EE + 255) / 256, 256, 0, stream>>>(row1, col1, val1, rp1, cur, cols1,
                                                         vals1);
    // ---- CSR build, graph 2 ----
    hipMemsetAsync(cnt, 0, NN * 4, stream);
    hipMemsetAsync(cur, 0, NN * 4, stream);
    hist_kernel<<<(EE + 255) / 256, 256, 0, stream>>>(row2, cnt);
    scan_kernel<<<1, 1024, 0, stream>>>(cnt, rp2);
    scatter_kernel<<<(EE + 255) / 256, 256, 0, stream>>>(row2, col2, val2, rp2, cur, cols2,
                                                         vals2);

    hipMemsetAsync(s1, 0, NN * 4, stream);
    hipMemsetAsync(s2, 0, NN * 4, stream);

    auto branch = [&](const int* rp, const int* cols, const float* vals, float* sc) {
        spmm_kernel<<<NN / 4, 256, 0, stream>>>(rp, cols, vals, W0, xbuf, 1);
        mlp_kernel<<<(NN + 31) / 32, 256, 0, stream>>>(xbuf, L1w, L1b, L2w, L2b, L3w, L3b, sc);
        for (int l = 0; l < 4; ++l) {
            gemm128_kernel<<<(NN + 63) / 64, 256, 0, stream>>>(xbuf, Wg[l], ybuf);
            spmm_kernel<<<NN / 4, 256, 0, stream>>>(rp, cols, vals, ybuf, xbuf, l < 3 ? 1 : 0);
            mlp_kernel<<<(NN + 31) / 32, 256, 0, stream>>>(xbuf, L1w, L1b, L2w, L2b, L3w, L3b,
                                                           sc);
        }
    };
    branch(rp1, cols1, vals1, s1);
    branch(rp2, cols2, vals2, s2);

    final_kernel<<<(NN + 255) / 256, 256, 0, stream>>>(s1, s2, out);
}

// Round 3
// 1726.547 us; speedup vs baseline: 1.4227x; 1.4227x over previous
//
#include <hip/hip_runtime.h>

#define NN 50000
#define EE 250000
#define HD 128

typedef __attribute__((ext_vector_type(8))) short bf16x8;
typedef __attribute__((ext_vector_type(4))) float f32x4;

__device__ inline short f2bf(float f) {
    unsigned u = __builtin_bit_cast(unsigned, f);
    unsigned r = u + 0x7fffu + ((u >> 16) & 1u);
    return (short)(r >> 16);
}

// ---------------- CSR build ----------------
__global__ void hist_kernel(const int* __restrict__ row, int* __restrict__ cnt) {
    int e = blockIdx.x * blockDim.x + threadIdx.x;
    if (e < EE) atomicAdd(&cnt[row[e]], 1);
}

__global__ __launch_bounds__(1024) void scan_kernel(const int* __restrict__ cnt,
                                                    int* __restrict__ rp) {
    __shared__ int s[1024];
    int tid = threadIdx.x;
    int c0 = 0;
    for (int base = 0; base < NN; base += 8192) {
        int v[8];
        int sum = 0;
        int i0 = base + tid * 8;
#pragma unroll
        for (int j = 0; j < 8; ++j) {
            int i = i0 + j;
            v[j] = (i < NN) ? cnt[i] : 0;
            sum += v[j];
        }
        s[tid] = sum;
        __syncthreads();
        for (int off = 1; off < 1024; off <<= 1) {
            int t = (tid >= off) ? s[tid - off] : 0;
            __syncthreads();
            s[tid] += t;
            __syncthreads();
        }
        int excl = c0 + s[tid] - sum;
#pragma unroll
        for (int j = 0; j < 8; ++j) {
            int i = i0 + j;
            if (i < NN) rp[i] = excl;
            excl += v[j];
        }
        int tot = s[1023];
        __syncthreads();
        c0 += tot;
    }
    if (tid == 0) rp[NN] = c0;
}

__global__ void scatter_kernel(const int* __restrict__ row, const int* __restrict__ col,
                               const float* __restrict__ val, const int* __restrict__ rp,
                               int* __restrict__ cur, int* __restrict__ cols_s,
                               float* __restrict__ vals_s) {
    int e = blockIdx.x * blockDim.x + threadIdx.x;
    if (e >= EE) return;
    int r = row[e];
    int p = atomicAdd(&cur[r], 1);
    int d = rp[r] + p;
    cols_s[d] = col[e];
    vals_s[d] = val[e];
}

// ---------------- weight transpose + bf16 convert (N fixed = 256) ----------------
__global__ void tcvt_kernel(const float* __restrict__ in, short* __restrict__ out, int K) {
    int i = blockIdx.x * 256 + threadIdx.x;
    if (i >= K * 256) return;
    int k = i >> 8, n = i & 255;
    out[n * K + k] = f2bf(in[i]);
}

// ---------------- SpMM (CSR) + ReLU (+ l2norm); also emits bf16 copy ----------------
__global__ __launch_bounds__(256) void spmm_kernel(const int* __restrict__ rp,
                                                   const int* __restrict__ cols,
                                                   const float* __restrict__ vals,
                                                   const float* __restrict__ xin,
                                                   float* __restrict__ xout,
                                                   unsigned short* __restrict__ xh,
                                                   int do_norm) {
    int w = (blockIdx.x * 256 + threadIdx.x) >> 6;
    int lane = threadIdx.x & 63;
    if (w >= NN) return;
    int beg = rp[w], end = rp[w + 1];
    float ax = 0.f, ay = 0.f;
    for (int e = beg; e < end; ++e) {
        int c = cols[e];
        float v = vals[e];
        const float2 xr = *(const float2*)(xin + (size_t)c * HD + lane * 2);
        ax = fmaf(v, xr.x, ax);
        ay = fmaf(v, xr.y, ay);
    }
    ax = fmaxf(ax, 0.f);
    ay = fmaxf(ay, 0.f);
    if (do_norm) {
        float ss = ax * ax + ay * ay;
#pragma unroll
        for (int off = 32; off > 0; off >>= 1) ss += __shfl_xor(ss, off, 64);
        float scale = 1.f / fmaxf(sqrtf(ss), 1e-12f);
        ax *= scale;
        ay *= scale;
    }
    float2 o;
    o.x = ax;
    o.y = ay;
    *(float2*)(xout + (size_t)w * HD + lane * 2) = o;
    ushort2 oh;
    oh.x = (unsigned short)f2bf(ax);
    oh.y = (unsigned short)f2bf(ay);
    *(ushort2*)(xh + (size_t)w * HD + lane * 2) = oh;
}

// ---------------- dense GEMM: y = x @ W (W is 128x128), fp32 VALU ----------------
__global__ __launch_bounds__(256) void gemm128_kernel(const float* __restrict__ x,
                                                      const float* __restrict__ W,
                                                      float* __restrict__ y) {
    __shared__ float Xt[HD][68];
    int tile = blockIdx.x * 64;
    int tid = threadIdx.x;
#pragma unroll
    for (int it = 0; it < 8; ++it) {
        int idx = it * 256 + tid;
        int r = idx >> 5;
        int k4 = (idx & 31) * 4;
        float4 xv = make_float4(0.f, 0.f, 0.f, 0.f);
        if (tile + r < NN) xv = *(const float4*)(x + (size_t)(tile + r) * HD + k4);
        Xt[k4 + 0][r] = xv.x;
        Xt[k4 + 1][r] = xv.y;
        Xt[k4 + 2][r] = xv.z;
        Xt[k4 + 3][r] = xv.w;
    }
    __syncthreads();
    int cg = tid & 31, rg = tid >> 5;
    int c0 = cg * 4, r0 = rg * 8;
    float acc[8][4] = {};
    for (int k = 0; k < HD; ++k) {
        float4 wv = *(const float4*)(W + k * HD + c0);
        float4 xa = *(const float4*)(&Xt[k][r0]);
        float4 xb = *(const float4*)(&Xt[k][r0 + 4]);
        float xs[8] = {xa.x, xa.y, xa.z, xa.w, xb.x, xb.y, xb.z, xb.w};
        float wr[4] = {wv.x, wv.y, wv.z, wv.w};
#pragma unroll
        for (int i = 0; i < 8; ++i)
#pragma unroll
            for (int j = 0; j < 4; ++j) acc[i][j] = fmaf(xs[i], wr[j], acc[i][j]);
    }
#pragma unroll
    for (int i = 0; i < 8; ++i) {
        int r = tile + r0 + i;
        if (r < NN) {
            float4 o;
            o.x = acc[i][0];
            o.y = acc[i][1];
            o.z = acc[i][2];
            o.w = acc[i][3];
            *(float4*)(y + (size_t)r * HD + c0) = o;
        }
    }
}

// ---------------- fused MLP via bf16 MFMA: score[n] += mlp(x[n]) ----------------
// 64 nodes/block, 4 waves x 16 rows. A-frags in regs; H1 (64x256 bf16, XOR-swizzled)
// in LDS; layer-3 dot folded into layer-2 epilogue with 16-lane shfl reduce.
__global__ __launch_bounds__(256) void mlp_mfma_kernel(
    const unsigned short* __restrict__ xh, const short* __restrict__ W1t,
    const float* __restrict__ L1b, const short* __restrict__ W2t,
    const float* __restrict__ L2b, const float* __restrict__ L3w,
    const float* __restrict__ L3b, float* __restrict__ score) {
    __shared__ __align__(16) char H1s[64 * 512];  // 64 rows x 256 bf16
    int tid = threadIdx.x;
    int wave = tid >> 6, lane = tid & 63;
    int nl = lane & 15, kg = lane >> 4;
    int tile = blockIdx.x * 64;
    int rbase = wave * 16;

    // ---- A1 frags: 16 x-rows of this wave, K=128 (4 k-steps) ----
    int node = tile + rbase + nl;
    if (node >= NN) node = NN - 1;
    const short* xrow = (const short*)xh + (size_t)node * HD + kg * 8;
    bf16x8 a1[4];
#pragma unroll
    for (int ks = 0; ks < 4; ++ks) a1[ks] = *(const bf16x8*)(xrow + ks * 32);

    // ---- layer 1: H1 = relu(X @ W1 + b1)  (16 col-tiles of 16) ----
    f32x4 acc1[16];
#pragma unroll
    for (int ct = 0; ct < 16; ++ct) acc1[ct] = (f32x4){0.f, 0.f, 0.f, 0.f};
#pragma unroll
    for (int ct = 0; ct < 16; ++ct) {
        const short* wb = W1t + (ct * 16 + nl) * 128 + kg * 8;
#pragma unroll
        for (int ks = 0; ks < 4; ++ks) {
            bf16x8 b = *(const bf16x8*)(wb + ks * 32);
            acc1[ct] = __builtin_amdgcn_mfma_f32_16x16x32_bf16(a1[ks], b, acc1[ct], 0, 0, 0);
        }
    }
#pragma unroll
    for (int ct = 0; ct < 16; ++ct) {
        float bia = L1b[ct * 16 + nl];
#pragma unroll
        for (int reg = 0; reg < 4; ++reg) {
            float h = fmaxf(acc1[ct][reg] + bia, 0.f);
            int r = rbase + kg * 4 + reg;  // block-local row
            int bytes = (r * 512 + ct * 32 + nl * 2) ^ ((r & 7) << 4);
            *(short*)(H1s + bytes) = f2bf(h);
        }
    }
    __syncthreads();

    // ---- A2 frags from LDS (swizzled), K=256 (8 k-steps) ----
    int r2 = rbase + nl;
    bf16x8 a2[8];
#pragma unroll
    for (int ks = 0; ks < 8; ++ks) {
        int bytes = (r2 * 512 + ks * 64 + kg * 16) ^ ((r2 & 7) << 4);
        a2[ks] = *(const bf16x8*)(H1s + bytes);
    }

    // ---- layer 2: acc2 = H1 @ W2 ----
    f32x4 acc2[16];
#pragma unroll
    for (int ct = 0; ct < 16; ++ct) acc2[ct] = (f32x4){0.f, 0.f, 0.f, 0.f};
#pragma unroll
    for (int ct = 0; ct < 16; ++ct) {
        const short* wb = W2t + (ct * 16 + nl) * 256 + kg * 8;
#pragma unroll
        for (int ks = 0; ks < 8; ++ks) {
            bf16x8 b = *(const bf16x8*)(wb + ks * 32);
            acc2[ct] = __builtin_amdgcn_mfma_f32_16x16x32_bf16(a2[ks], b, acc2[ct], 0, 0, 0);
        }
    }

    // ---- layer 2 epilogue + layer 3 dot (fp32) ----
    float t[4] = {0.f, 0.f, 0.f, 0.f};
#pragma unroll
    for (int ct = 0; ct < 16; ++ct) {
        int n = ct * 16 + nl;
        float b2 = L2b[n], w3 = L3w[n];
#pragma unroll
        for (int reg = 0; reg < 4; ++reg)
            t[reg] = fmaf(fmaxf(acc2[ct][reg] + b2, 0.f), w3, t[reg]);
    }
#pragma unroll
    for (int off = 1; off < 16; off <<= 1)
#pragma unroll
        for (int reg = 0; reg < 4; ++reg) t[reg] += __shfl_xor(t[reg], off, 64);
    if (nl == 0) {
        float b3 = L3b[0];
#pragma unroll
        for (int reg = 0; reg < 4; ++reg) {
            int g = tile + rbase + kg * 4 + reg;
            if (g < NN) score[g] += t[reg] + b3;
        }
    }
}

__global__ void final_kernel(const float* __restrict__ s1, const float* __restrict__ s2,
                             float* __restrict__ out) {
    int i = blockIdx.x * blockDim.x + threadIdx.x;
    if (i < NN) out[i] = s1[i] * s2[i];
}

extern "C" void kernel_launch(void* const* d_in, const int* in_sizes, int n_in,
                              void* d_out, int out_size, void* d_ws, size_t ws_size,
                              hipStream_t stream) {
    const int* row1 = (const int*)d_in[0];
    const int* col1 = (const int*)d_in[1];
    const float* val1 = (const float*)d_in[2];
    const int* row2 = (const int*)d_in[3];
    const int* col2 = (const int*)d_in[4];
    const float* val2 = (const float*)d_in[5];
    const float* W0 = (const float*)d_in[6];
    const float* Wg[4] = {(const float*)d_in[7], (const float*)d_in[8], (const float*)d_in[9],
                          (const float*)d_in[10]};
    const float* L1w = (const float*)d_in[11];
    const float* L1b = (const float*)d_in[12];
    const float* L2w = (const float*)d_in[13];
    const float* L2b = (const float*)d_in[14];
    const float* L3w = (const float*)d_in[15];
    const float* L3b = (const float*)d_in[16];
    float* out = (float*)d_out;

    char* ws = (char*)d_ws;
    size_t off = 0;
    auto alloc = [&](size_t bytes) {
        void* p = ws + off;
        off = (off + bytes + 255) & ~(size_t)255;
        return p;
    };
    int* rp1 = (int*)alloc((NN + 1) * 4);
    int* cols1 = (int*)alloc(EE * 4);
    float* vals1 = (float*)alloc(EE * 4);
    int* rp2 = (int*)alloc((NN + 1) * 4);
    int* cols2 = (int*)alloc(EE * 4);
    float* vals2 = (float*)alloc(EE * 4);
    int* cnt = (int*)alloc(NN * 4);
    int* cur = (int*)alloc(NN * 4);
    float* xbuf = (float*)alloc((size_t)NN * HD * 4);
    float* ybuf = (float*)alloc((size_t)NN * HD * 4);
    float* s1 = (float*)alloc(NN * 4);
    float* s2 = (float*)alloc(NN * 4);
    unsigned short* xh = (unsigned short*)alloc((size_t)NN * HD * 2);
    short* W1t = (short*)alloc(256 * 128 * 2);
    short* W2t = (short*)alloc(256 * 256 * 2);

    // ---- weight prep (bf16, transposed) ----
    tcvt_kernel<<<(128 * 256 + 255) / 256, 256, 0, stream>>>(L1w, W1t, 128);
    tcvt_kernel<<<(256 * 256 + 255) / 256, 256, 0, stream>>>(L2w, W2t, 256);

    // ---- CSR build, graph 1 ----
    hipMemsetAsync(cnt, 0, NN * 4, stream);
    hipMemsetAsync(cur, 0, NN * 4, stream);
    hist_kernel<<<(EE + 255) / 256, 256, 0, stream>>>(row1, cnt);
    scan_kernel<<<1, 1024, 0, stream>>>(cnt, rp1);
    scatter_kernel<<<(EE + 255) / 256, 256, 0, stream>>>(row1, col1, val1, rp1, cur, cols1,
                                                         vals1);
    // ---- CSR build, graph 2 ----
    hipMemsetAsync(cnt, 0, NN * 4, stream);
    hipMemsetAsync(cur, 0, NN * 4, stream);
    hist_kernel<<<(EE + 255) / 256, 256, 0, stream>>>(row2, cnt);
    scan_kernel<<<1, 1024, 0, stream>>>(cnt, rp2);
    scatter_kernel<<<(EE + 255) / 256, 256, 0, stream>>>(row2, col2, val2, rp2, cur, cols2,
                                                         vals2);

    hipMemsetAsync(s1, 0, NN * 4, stream);
    hipMemsetAsync(s2, 0, NN * 4, stream);

    auto branch = [&](const int* rp, const int* cols, const float* vals, float* sc) {
        spmm_kernel<<<NN / 4, 256, 0, stream>>>(rp, cols, vals, W0, xbuf, xh, 1);
        mlp_mfma_kernel<<<(NN + 63) / 64, 256, 0, stream>>>(xh, W1t, L1b, W2t, L2b, L3w, L3b,
                                                            sc);
        for (int l = 0; l < 4; ++l) {
            gemm128_kernel<<<(NN + 63) / 64, 256, 0, stream>>>(xbuf, Wg[l], ybuf);
            spmm_kernel<<<NN / 4, 256, 0, stream>>>(rp, cols, vals, ybuf, xbuf, xh, l < 3 ? 1 : 0);
            mlp_mfma_kernel<<<(NN + 63) / 64, 256, 0, stream>>>(xh, W1t, L1b, W2t, L2b, L3w,
                                                                L3b, sc);
        }
    };
    branch(rp1, cols1, vals1, s1);
    branch(rp2, cols2, vals2, s2);

    final_kernel<<<(NN + 255) / 256, 256, 0, stream>>>(s1, s2, out);
}

// Round 4
// 1031.467 us; speedup vs baseline: 2.3815x; 1.6739x over previous
//
#include <hip/hip_runtime.h>

#define NN 50000
#define EE 250000
#define HD 128

typedef __attribute__((ext_vector_type(8))) short bf16x8;
typedef __attribute__((ext_vector_type(4))) float f32x4;

__device__ inline short f2bf(float f) {
    unsigned u = __builtin_bit_cast(unsigned, f);
    unsigned r = u + 0x7fffu + ((u >> 16) & 1u);
    return (short)(r >> 16);
}

// ---------------- CSR build ----------------
__global__ void hist_kernel(const int* __restrict__ row, int* __restrict__ cnt) {
    int e = blockIdx.x * blockDim.x + threadIdx.x;
    if (e < EE) atomicAdd(&cnt[row[e]], 1);
}

__global__ __launch_bounds__(1024) void scan_kernel(const int* __restrict__ cnt,
                                                    int* __restrict__ rp) {
    __shared__ int s[1024];
    int tid = threadIdx.x;
    int c0 = 0;
    for (int base = 0; base < NN; base += 8192) {
        int v[8];
        int sum = 0;
        int i0 = base + tid * 8;
#pragma unroll
        for (int j = 0; j < 8; ++j) {
            int i = i0 + j;
            v[j] = (i < NN) ? cnt[i] : 0;
            sum += v[j];
        }
        s[tid] = sum;
        __syncthreads();
        for (int off = 1; off < 1024; off <<= 1) {
            int t = (tid >= off) ? s[tid - off] : 0;
            __syncthreads();
            s[tid] += t;
            __syncthreads();
        }
        int excl = c0 + s[tid] - sum;
#pragma unroll
        for (int j = 0; j < 8; ++j) {
            int i = i0 + j;
            if (i < NN) rp[i] = excl;
            excl += v[j];
        }
        int tot = s[1023];
        __syncthreads();
        c0 += tot;
    }
    if (tid == 0) rp[NN] = c0;
}

__global__ void scatter_kernel(const int* __restrict__ row, const int* __restrict__ col,
                               const float* __restrict__ val, const int* __restrict__ rp,
                               int* __restrict__ cur, int* __restrict__ cols_s,
                               float* __restrict__ vals_s) {
    int e = blockIdx.x * blockDim.x + threadIdx.x;
    if (e >= EE) return;
    int r = row[e];
    int p = atomicAdd(&cur[r], 1);
    int d = rp[r] + p;
    cols_s[d] = col[e];
    vals_s[d] = val[e];
}

// ---- pack W (K x 256 row-major fp32) into MFMA A'-fragment order, bf16 ----
// frag f = ct*NKS + ks holds the 16x32 tile A'[c=ct*16+nl][k=ks*32+kg*8+j],
// laid out contiguously: out[f*512 + lane*8 + j], lane = kg*16+nl.
__global__ void pack_kernel(const float* __restrict__ in, short* __restrict__ out, int NKS) {
    int t = blockIdx.x * 256 + threadIdx.x;
    if (t >= 16 * NKS * 64) return;
    int lane = t & 63, f = t >> 6;
    int ks = f % NKS, ct = f / NKS;
    int nl = lane & 15, kg = lane >> 4;
    int c = ct * 16 + nl;
    bf16x8 o;
#pragma unroll
    for (int j = 0; j < 8; ++j) {
        int k = ks * 32 + kg * 8 + j;
        o[j] = f2bf(in[k * 256 + c]);
    }
    *(bf16x8*)(out + f * 512 + lane * 8) = o;
}

// ---------------- SpMM (CSR) + ReLU (+ l2norm); also emits bf16 copy ----------------
__global__ __launch_bounds__(256) void spmm_kernel(const int* __restrict__ rp,
                                                   const int* __restrict__ cols,
                                                   const float* __restrict__ vals,
                                                   const float* __restrict__ xin,
                                                   float* __restrict__ xout,
                                                   unsigned short* __restrict__ xh,
                                                   int do_norm) {
    int w = (blockIdx.x * 256 + threadIdx.x) >> 6;
    int lane = threadIdx.x & 63;
    if (w >= NN) return;
    int beg = rp[w], end = rp[w + 1];
    float ax = 0.f, ay = 0.f;
    for (int e = beg; e < end; ++e) {
        int c = cols[e];
        float v = vals[e];
        const float2 xr = *(const float2*)(xin + (size_t)c * HD + lane * 2);
        ax = fmaf(v, xr.x, ax);
        ay = fmaf(v, xr.y, ay);
    }
    ax = fmaxf(ax, 0.f);
    ay = fmaxf(ay, 0.f);
    if (do_norm) {
        float ss = ax * ax + ay * ay;
#pragma unroll
        for (int off = 32; off > 0; off >>= 1) ss += __shfl_xor(ss, off, 64);
        float scale = 1.f / fmaxf(sqrtf(ss), 1e-12f);
        ax *= scale;
        ay *= scale;
    }
    float2 o;
    o.x = ax;
    o.y = ay;
    *(float2*)(xout + (size_t)w * HD + lane * 2) = o;
    ushort2 oh;
    oh.x = (unsigned short)f2bf(ax);
    oh.y = (unsigned short)f2bf(ay);
    *(ushort2*)(xh + (size_t)w * HD + lane * 2) = oh;
}

// ---------------- dense GEMM: y = x @ W (W is 128x128), fp32 VALU ----------------
__global__ __launch_bounds__(256) void gemm128_kernel(const float* __restrict__ x,
                                                      const float* __restrict__ W,
                                                      float* __restrict__ y) {
    __shared__ float Xt[HD][68];
    int tile = blockIdx.x * 64;
    int tid = threadIdx.x;
#pragma unroll
    for (int it = 0; it < 8; ++it) {
        int idx = it * 256 + tid;
        int r = idx >> 5;
        int k4 = (idx & 31) * 4;
        float4 xv = make_float4(0.f, 0.f, 0.f, 0.f);
        if (tile + r < NN) xv = *(const float4*)(x + (size_t)(tile + r) * HD + k4);
        Xt[k4 + 0][r] = xv.x;
        Xt[k4 + 1][r] = xv.y;
        Xt[k4 + 2][r] = xv.z;
        Xt[k4 + 3][r] = xv.w;
    }
    __syncthreads();
    int cg = tid & 31, rg = tid >> 5;
    int c0 = cg * 4, r0 = rg * 8;
    float acc[8][4] = {};
    for (int k = 0; k < HD; ++k) {
        float4 wv = *(const float4*)(W + k * HD + c0);
        float4 xa = *(const float4*)(&Xt[k][r0]);
        float4 xb = *(const float4*)(&Xt[k][r0 + 4]);
        float xs[8] = {xa.x, xa.y, xa.z, xa.w, xb.x, xb.y, xb.z, xb.w};
        float wr[4] = {wv.x, wv.y, wv.z, wv.w};
#pragma unroll
        for (int i = 0; i < 8; ++i)
#pragma unroll
            for (int j = 0; j < 4; ++j) acc[i][j] = fmaf(xs[i], wr[j], acc[i][j]);
    }
#pragma unroll
    for (int i = 0; i < 8; ++i) {
        int r = tile + r0 + i;
        if (r < NN) {
            float4 o;
            o.x = acc[i][0];
            o.y = acc[i][1];
            o.z = acc[i][2];
            o.w = acc[i][3];
            *(float4*)(y + (size_t)r * HD + c0) = o;
        }
    }
}

// ---------------- fused MLP via bf16 MFMA, M-rep=4 ----------------
// 256 nodes/block, 4 waves x 64 rows. Swapped operands: mfma(Wfrag, Xfrag)
// -> lane holds output row r=nl. H1 per-wave private (32KB, XOR-swizzled),
// no __syncthreads. W pre-packed in fragment order (coalesced 1KB loads).
__global__ __launch_bounds__(256) void mlp_mfma_kernel(
    const unsigned short* __restrict__ xh, const short* __restrict__ W1p,
    const float* __restrict__ L1b, const short* __restrict__ W2p,
    const float* __restrict__ L2b, const float* __restrict__ L3w,
    const float* __restrict__ L3b, float* __restrict__ score) {
    __shared__ __align__(16) char H1s[131072];  // 4 waves x (64 rows x 512B)
    int tid = threadIdx.x;
    int wave = tid >> 6, lane = tid & 63;
    int nl = lane & 15, kg = lane >> 4;
    int tile = blockIdx.x * 256;
    int rowbase = wave * 64;
    char* myH = H1s + wave * 32768;

    // ---- A1 (X as B-operand): 4 m-tiles x 4 k-steps ----
    bf16x8 a1[4][4];
#pragma unroll
    for (int m = 0; m < 4; ++m) {
        int node = tile + rowbase + m * 16 + nl;
        if (node >= NN) node = NN - 1;
        const short* xr = (const short*)xh + (size_t)node * HD + kg * 8;
#pragma unroll
        for (int ks = 0; ks < 4; ++ks) a1[m][ks] = *(const bf16x8*)(xr + ks * 32);
    }

    // ---- layer 1: H1^T fragments; lane holds rows r=nl, cols ct*16+kg*4+reg ----
#pragma unroll
    for (int ct = 0; ct < 16; ++ct) {
        bf16x8 w[4];
#pragma unroll
        for (int ks = 0; ks < 4; ++ks)
            w[ks] = *(const bf16x8*)(W1p + (ct * 4 + ks) * 512 + lane * 8);
        f32x4 acc[4];
#pragma unroll
        for (int m = 0; m < 4; ++m) acc[m] = (f32x4){0.f, 0.f, 0.f, 0.f};
#pragma unroll
        for (int ks = 0; ks < 4; ++ks)
#pragma unroll
            for (int m = 0; m < 4; ++m)
                acc[m] = __builtin_amdgcn_mfma_f32_16x16x32_bf16(w[ks], a1[m][ks], acc[m], 0, 0, 0);
        float4 b1v = *(const float4*)(L1b + ct * 16 + kg * 4);
#pragma unroll
        for (int m = 0; m < 4; ++m) {
            short4 hs;
            hs.x = f2bf(fmaxf(acc[m][0] + b1v.x, 0.f));
            hs.y = f2bf(fmaxf(acc[m][1] + b1v.y, 0.f));
            hs.z = f2bf(fmaxf(acc[m][2] + b1v.z, 0.f));
            hs.w = f2bf(fmaxf(acc[m][3] + b1v.w, 0.f));
            int r = m * 16 + nl;
            int byte = (r * 512 + ct * 32 + kg * 8) ^ ((r & 7) << 4);
            *(short4*)(myH + byte) = hs;
        }
    }

    // ---- A2 from LDS: row nl of each m-tile, 8 k-steps ----
    bf16x8 a2[4][8];
#pragma unroll
    for (int m = 0; m < 4; ++m) {
        int r = m * 16 + nl;
#pragma unroll
        for (int ks = 0; ks < 8; ++ks) {
            int byte = (r * 512 + ks * 64 + kg * 16) ^ ((r & 7) << 4);
            a2[m][ks] = *(const bf16x8*)(myH + byte);
        }
    }

    // ---- layer 2 + fused layer-3 dot ----
    float t[4] = {0.f, 0.f, 0.f, 0.f};
#pragma unroll
    for (int ct = 0; ct < 16; ++ct) {
        bf16x8 w[8];
#pragma unroll
        for (int ks = 0; ks < 8; ++ks)
            w[ks] = *(const bf16x8*)(W2p + (ct * 8 + ks) * 512 + lane * 8);
        f32x4 acc[4];
#pragma unroll
        for (int m = 0; m < 4; ++m) acc[m] = (f32x4){0.f, 0.f, 0.f, 0.f};
#pragma unroll
        for (int ks = 0; ks < 8; ++ks)
#pragma unroll
            for (int m = 0; m < 4; ++m)
                acc[m] = __builtin_amdgcn_mfma_f32_16x16x32_bf16(w[ks], a2[m][ks], acc[m], 0, 0, 0);
        float4 b2v = *(const float4*)(L2b + ct * 16 + kg * 4);
        float4 w3v = *(const float4*)(L3w + ct * 16 + kg * 4);
#pragma unroll
        for (int m = 0; m < 4; ++m) {
            t[m] = fmaf(fmaxf(acc[m][0] + b2v.x, 0.f), w3v.x, t[m]);
            t[m] = fmaf(fmaxf(acc[m][1] + b2v.y, 0.f), w3v.y, t[m]);
            t[m] = fmaf(fmaxf(acc[m][2] + b2v.z, 0.f), w3v.z, t[m]);
            t[m] = fmaf(fmaxf(acc[m][3] + b2v.w, 0.f), w3v.w, t[m]);
        }
    }
#pragma unroll
    for (int m = 0; m < 4; ++m) {
        t[m] += __shfl_xor(t[m], 16, 64);
        t[m] += __shfl_xor(t[m], 32, 64);
    }
    if (kg == 0) {
        float b3 = L3b[0];
#pragma unroll
        for (int m = 0; m < 4; ++m) {
            int g = tile + rowbase + m * 16 + nl;
            if (g < NN) score[g] += t[m] + b3;
        }
    }
}

__global__ void final_kernel(const float* __restrict__ s1, const float* __restrict__ s2,
                             float* __restrict__ out) {
    int i = blockIdx.x * blockDim.x + threadIdx.x;
    if (i < NN) out[i] = s1[i] * s2[i];
}

extern "C" void kernel_launch(void* const* d_in, const int* in_sizes, int n_in,
                              void* d_out, int out_size, void* d_ws, size_t ws_size,
                              hipStream_t stream) {
    const int* row1 = (const int*)d_in[0];
    const int* col1 = (const int*)d_in[1];
    const float* val1 = (const float*)d_in[2];
    const int* row2 = (const int*)d_in[3];
    const int* col2 = (const int*)d_in[4];
    const float* val2 = (const float*)d_in[5];
    const float* W0 = (const float*)d_in[6];
    const float* Wg[4] = {(const float*)d_in[7], (const float*)d_in[8], (const float*)d_in[9],
                          (const float*)d_in[10]};
    const float* L1w = (const float*)d_in[11];
    const float* L1b = (const float*)d_in[12];
    const float* L2w = (const float*)d_in[13];
    const float* L2b = (const float*)d_in[14];
    const float* L3w = (const float*)d_in[15];
    const float* L3b = (const float*)d_in[16];
    float* out = (float*)d_out;

    char* ws = (char*)d_ws;
    size_t off = 0;
    auto alloc = [&](size_t bytes) {
        void* p = ws + off;
        off = (off + bytes + 255) & ~(size_t)255;
        return p;
    };
    int* rp1 = (int*)alloc((NN + 1) * 4);
    int* cols1 = (int*)alloc(EE * 4);
    float* vals1 = (float*)alloc(EE * 4);
    int* rp2 = (int*)alloc((NN + 1) * 4);
    int* cols2 = (int*)alloc(EE * 4);
    float* vals2 = (float*)alloc(EE * 4);
    int* cnt = (int*)alloc(NN * 4);
    int* cur = (int*)alloc(NN * 4);
    float* xbuf = (float*)alloc((size_t)NN * HD * 4);
    float* ybuf = (float*)alloc((size_t)NN * HD * 4);
    float* s1 = (float*)alloc(NN * 4);
    float* s2 = (float*)alloc(NN * 4);
    unsigned short* xh = (unsigned short*)alloc((size_t)NN * HD * 2);
    short* W1p = (short*)alloc(16 * 4 * 512 * 2);
    short* W2p = (short*)alloc(16 * 8 * 512 * 2);

    // ---- weight prep (bf16, MFMA fragment order) ----
    pack_kernel<<<(16 * 4 * 64 + 255) / 256, 256, 0, stream>>>(L1w, W1p, 4);
    pack_kernel<<<(16 * 8 * 64 + 255) / 256, 256, 0, stream>>>(L2w, W2p, 8);

    // ---- CSR build, graph 1 ----
    hipMemsetAsync(cnt, 0, NN * 4, stream);
    hipMemsetAsync(cur, 0, NN * 4, stream);
    hist_kernel<<<(EE + 255) / 256, 256, 0, stream>>>(row1, cnt);
    scan_kernel<<<1, 1024, 0, stream>>>(cnt, rp1);
    scatter_kernel<<<(EE + 255) / 256, 256, 0, stream>>>(row1, col1, val1, rp1, cur, cols1,
                                                         vals1);
    // ---- CSR build, graph 2 ----
    hipMemsetAsync(cnt, 0, NN * 4, stream);
    hipMemsetAsync(cur, 0, NN * 4, stream);
    hist_kernel<<<(EE + 255) / 256, 256, 0, stream>>>(row2, cnt);
    scan_kernel<<<1, 1024, 0, stream>>>(cnt, rp2);
    scatter_kernel<<<(EE + 255) / 256, 256, 0, stream>>>(row2, col2, val2, rp2, cur, cols2,
                                                         vals2);

    hipMemsetAsync(s1, 0, NN * 4, stream);
    hipMemsetAsync(s2, 0, NN * 4, stream);

    auto branch = [&](const int* rp, const int* cols, const float* vals, float* sc) {
        spmm_kernel<<<NN / 4, 256, 0, stream>>>(rp, cols, vals, W0, xbuf, xh, 1);
        mlp_mfma_kernel<<<(NN + 255) / 256, 256, 0, stream>>>(xh, W1p, L1b, W2p, L2b, L3w, L3b,
                                                              sc);
        for (int l = 0; l < 4; ++l) {
            gemm128_kernel<<<(NN + 63) / 64, 256, 0, stream>>>(xbuf, Wg[l], ybuf);
            spmm_kernel<<<NN / 4, 256, 0, stream>>>(rp, cols, vals, ybuf, xbuf, xh, l < 3 ? 1 : 0);
            mlp_mfma_kernel<<<(NN + 255) / 256, 256, 0, stream>>>(xh, W1p, L1b, W2p, L2b, L3w,
                                                                  L3b, sc);
        }
    };
    branch(rp1, cols1, vals1, s1);
    branch(rp2, cols2, vals2, s2);

    final_kernel<<<(NN + 255) / 256, 256, 0, stream>>>(s1, s2, out);
}

// Round 5
// 910.796 us; speedup vs baseline: 2.6970x; 1.1325x over previous
//
#include <hip/hip_runtime.h>

#define NN 50000
#define EE 250000
#define HD 128

typedef __attribute__((ext_vector_type(8))) short bf16x8;
typedef __attribute__((ext_vector_type(4))) float f32x4;

__device__ inline short f2bf(float f) {
    unsigned u = __builtin_bit_cast(unsigned, f);
    unsigned r = u + 0x7fffu + ((u >> 16) & 1u);
    return (short)(r >> 16);
}
__device__ inline float bf2f(short h) {
    unsigned u = ((unsigned)(unsigned short)h) << 16;
    return __builtin_bit_cast(float, u);
}

// ---------------- CSR build ----------------
__global__ void hist_kernel(const int* __restrict__ row, int* __restrict__ cnt) {
    int e = blockIdx.x * blockDim.x + threadIdx.x;
    if (e < EE) atomicAdd(&cnt[row[e]], 1);
}

__global__ __launch_bounds__(1024) void scan_kernel(const int* __restrict__ cnt,
                                                    int* __restrict__ rp) {
    __shared__ int s[1024];
    int tid = threadIdx.x;
    int c0 = 0;
    for (int base = 0; base < NN; base += 8192) {
        int v[8];
        int sum = 0;
        int i0 = base + tid * 8;
#pragma unroll
        for (int j = 0; j < 8; ++j) {
            int i = i0 + j;
            v[j] = (i < NN) ? cnt[i] : 0;
            sum += v[j];
        }
        s[tid] = sum;
        __syncthreads();
        for (int off = 1; off < 1024; off <<= 1) {
            int t = (tid >= off) ? s[tid - off] : 0;
            __syncthreads();
            s[tid] += t;
            __syncthreads();
        }
        int excl = c0 + s[tid] - sum;
#pragma unroll
        for (int j = 0; j < 8; ++j) {
            int i = i0 + j;
            if (i < NN) rp[i] = excl;
            excl += v[j];
        }
        int tot = s[1023];
        __syncthreads();
        c0 += tot;
    }
    if (tid == 0) rp[NN] = c0;
}

__global__ void scatter_kernel(const int* __restrict__ row, const int* __restrict__ col,
                               const float* __restrict__ val, const int* __restrict__ rp,
                               int* __restrict__ cur, int* __restrict__ cols_s,
                               float* __restrict__ vals_s) {
    int e = blockIdx.x * blockDim.x + threadIdx.x;
    if (e >= EE) return;
    int r = row[e];
    int p = atomicAdd(&cur[r], 1);
    int d = rp[r] + p;
    cols_s[d] = col[e];
    vals_s[d] = val[e];
}

// ---- pack W (K x NCOL row-major fp32) into MFMA A'-fragment order, bf16 ----
// frag f = ct*NKS + ks: 16x32 tile W^T[c=ct*16+nl][k=ks*32+kg*8+j],
// contiguous: out[f*512 + lane*8 + j].  lo=1 emits the bf16 residual.
__global__ void pack_kernel(const float* __restrict__ in, short* __restrict__ out, int NCOL,
                            int NKS, int lo) {
    int total = (NCOL / 16) * NKS * 64;
    int t = blockIdx.x * 256 + threadIdx.x;
    if (t >= total) return;
    int lane = t & 63, f = t >> 6;
    int ks = f % NKS, ct = f / NKS;
    int nl = lane & 15, kg = lane >> 4;
    int c = ct * 16 + nl;
    bf16x8 o;
#pragma unroll
    for (int j = 0; j < 8; ++j) {
        int k = ks * 32 + kg * 8 + j;
        float v = in[k * NCOL + c];
        short h = f2bf(v);
        o[j] = lo ? f2bf(v - bf2f(h)) : h;
    }
    *(bf16x8*)(out + f * 512 + lane * 8) = o;
}

// ---------------- SpMM layer-1: out = l2norm(relu(A @ W0)), fp32 + bf16 ----
// 2 rows/wave, 32 lanes x float4; edge loop unrolled x4 branch-free.
__global__ __launch_bounds__(256) void spmm_norm_kernel(
    const int* __restrict__ rp, const int* __restrict__ cols, const float* __restrict__ vals,
    const float* __restrict__ xin, float* __restrict__ xout, unsigned short* __restrict__ xh) {
    int r = (blockIdx.x * 256 + threadIdx.x) >> 5;
    int ln = threadIdx.x & 31;
    if (r >= NN) return;
    int beg = rp[r], end = rp[r + 1];
    float4 acc = make_float4(0.f, 0.f, 0.f, 0.f);
    for (int e = beg; e < end; e += 4) {
#pragma unroll
        for (int i = 0; i < 4; ++i) {
            int ei = e + i;
            int idx = ei < end ? ei : end - 1;
            int c = cols[idx];
            float v = ei < end ? vals[idx] : 0.f;
            float4 xr = *(const float4*)(xin + (size_t)c * HD + ln * 4);
            acc.x = fmaf(v, xr.x, acc.x);
            acc.y = fmaf(v, xr.y, acc.y);
            acc.z = fmaf(v, xr.z, acc.z);
            acc.w = fmaf(v, xr.w, acc.w);
        }
    }
    acc.x = fmaxf(acc.x, 0.f);
    acc.y = fmaxf(acc.y, 0.f);
    acc.z = fmaxf(acc.z, 0.f);
    acc.w = fmaxf(acc.w, 0.f);
    float ss = acc.x * acc.x + acc.y * acc.y + acc.z * acc.z + acc.w * acc.w;
#pragma unroll
    for (int off = 1; off < 32; off <<= 1) ss += __shfl_xor(ss, off, 64);
    float sc = 1.f / fmaxf(sqrtf(ss), 1e-12f);
    acc.x *= sc;
    acc.y *= sc;
    acc.z *= sc;
    acc.w *= sc;
    *(float4*)(xout + (size_t)r * HD + ln * 4) = acc;
    short4 hs;
    hs.x = f2bf(acc.x);
    hs.y = f2bf(acc.y);
    hs.z = f2bf(acc.z);
    hs.w = f2bf(acc.w);
    *(short4*)(xh + (size_t)r * HD + ln * 4) = hs;
}

// ---------------- SpMM raw: z = A @ x, emitted as split bf16 (zh + zl) ----
__global__ __launch_bounds__(256) void spmm_raw_kernel(
    const int* __restrict__ rp, const int* __restrict__ cols, const float* __restrict__ vals,
    const float* __restrict__ xin, short* __restrict__ zh, short* __restrict__ zl) {
    int r = (blockIdx.x * 256 + threadIdx.x) >> 5;
    int ln = threadIdx.x & 31;
    if (r >= NN) return;
    int beg = rp[r], end = rp[r + 1];
    float4 acc = make_float4(0.f, 0.f, 0.f, 0.f);
    for (int e = beg; e < end; e += 4) {
#pragma unroll
        for (int i = 0; i < 4; ++i) {
            int ei = e + i;
            int idx = ei < end ? ei : end - 1;
            int c = cols[idx];
            float v = ei < end ? vals[idx] : 0.f;
            float4 xr = *(const float4*)(xin + (size_t)c * HD + ln * 4);
            acc.x = fmaf(v, xr.x, acc.x);
            acc.y = fmaf(v, xr.y, acc.y);
            acc.z = fmaf(v, xr.z, acc.z);
            acc.w = fmaf(v, xr.w, acc.w);
        }
    }
    short4 hh, hl;
    hh.x = f2bf(acc.x);
    hl.x = f2bf(acc.x - bf2f(hh.x));
    hh.y = f2bf(acc.y);
    hl.y = f2bf(acc.y - bf2f(hh.y));
    hh.z = f2bf(acc.z);
    hl.z = f2bf(acc.z - bf2f(hh.z));
    hh.w = f2bf(acc.w);
    hl.w = f2bf(acc.w - bf2f(hh.w));
    *(short4*)(zh + (size_t)r * HD + ln * 4) = hh;
    *(short4*)(zl + (size_t)r * HD + ln * 4) = hl;
}

// ---------------- dense layer via MFMA (split bf16 ~ fp32 precision) ----------------
// x_next = [l2norm](relu(z @ W)); z given as zh+zl, W as packed Wh+Wl.
// 256 rows/block, 4 waves x 64 rows, M-rep=4, swapped operands (proven MLP layout).
// Norm path recomputes MFMAs (2-pass) instead of spilling acc: MFMA is cheap.
__global__ __launch_bounds__(256) void gemm_mfma_kernel(
    const short* __restrict__ zh, const short* __restrict__ zl, const short* __restrict__ Wh,
    const short* __restrict__ Wl, float* __restrict__ xout, unsigned short* __restrict__ xhout,
    int do_norm) {
    int tid = threadIdx.x;
    int wave = tid >> 6, lane = tid & 63;
    int nl = lane & 15, kg = lane >> 4;
    int tile = blockIdx.x * 256;
    int rowbase = wave * 64;

    bf16x8 ah[4][4], al[4][4];
#pragma unroll
    for (int m = 0; m < 4; ++m) {
        int node = tile + rowbase + m * 16 + nl;
        if (node >= NN) node = NN - 1;
        const short* ph = zh + (size_t)node * HD + kg * 8;
        const short* pl = zl + (size_t)node * HD + kg * 8;
#pragma unroll
        for (int ks = 0; ks < 4; ++ks) {
            ah[m][ks] = *(const bf16x8*)(ph + ks * 32);
            al[m][ks] = *(const bf16x8*)(pl + ks * 32);
        }
    }

    float scale[4] = {1.f, 1.f, 1.f, 1.f};
    if (do_norm) {
        float ss[4] = {0.f, 0.f, 0.f, 0.f};
#pragma unroll 1
        for (int ct = 0; ct < 8; ++ct) {
            bf16x8 wh[4], wl[4];
#pragma unroll
            for (int ks = 0; ks < 4; ++ks) {
                wh[ks] = *(const bf16x8*)(Wh + (ct * 4 + ks) * 512 + lane * 8);
                wl[ks] = *(const bf16x8*)(Wl + (ct * 4 + ks) * 512 + lane * 8);
            }
#pragma unroll
            for (int m = 0; m < 4; ++m) {
                f32x4 acc = (f32x4){0.f, 0.f, 0.f, 0.f};
#pragma unroll
                for (int ks = 0; ks < 4; ++ks) {
                    acc = __builtin_amdgcn_mfma_f32_16x16x32_bf16(wh[ks], ah[m][ks], acc, 0, 0, 0);
                    acc = __builtin_amdgcn_mfma_f32_16x16x32_bf16(wh[ks], al[m][ks], acc, 0, 0, 0);
                    acc = __builtin_amdgcn_mfma_f32_16x16x32_bf16(wl[ks], ah[m][ks], acc, 0, 0, 0);
                }
#pragma unroll
                for (int r = 0; r < 4; ++r) {
                    float y = fmaxf(acc[r], 0.f);
                    ss[m] = fmaf(y, y, ss[m]);
                }
            }
        }
#pragma unroll
        for (int m = 0; m < 4; ++m) {
            ss[m] += __shfl_xor(ss[m], 16, 64);
            ss[m] += __shfl_xor(ss[m], 32, 64);
            scale[m] = 1.f / fmaxf(sqrtf(ss[m]), 1e-12f);
        }
    }

#pragma unroll 1
    for (int ct = 0; ct < 8; ++ct) {
        bf16x8 wh[4], wl[4];
#pragma unroll
        for (int ks = 0; ks < 4; ++ks) {
            wh[ks] = *(const bf16x8*)(Wh + (ct * 4 + ks) * 512 + lane * 8);
            wl[ks] = *(const bf16x8*)(Wl + (ct * 4 + ks) * 512 + lane * 8);
        }
#pragma unroll
        for (int m = 0; m < 4; ++m) {
            f32x4 acc = (f32x4){0.f, 0.f, 0.f, 0.f};
#pragma unroll
            for (int ks = 0; ks < 4; ++ks) {
                acc = __builtin_amdgcn_mfma_f32_16x16x32_bf16(wh[ks], ah[m][ks], acc, 0, 0, 0);
                acc = __builtin_amdgcn_mfma_f32_16x16x32_bf16(wh[ks], al[m][ks], acc, 0, 0, 0);
                acc = __builtin_amdgcn_mfma_f32_16x16x32_bf16(wl[ks], ah[m][ks], acc, 0, 0, 0);
            }
            int node = tile + rowbase + m * 16 + nl;
            if (node < NN) {
                float4 o;
                o.x = fmaxf(acc[0], 0.f) * scale[m];
                o.y = fmaxf(acc[1], 0.f) * scale[m];
                o.z = fmaxf(acc[2], 0.f) * scale[m];
                o.w = fmaxf(acc[3], 0.f) * scale[m];
                *(float4*)(xout + (size_t)node * HD + ct * 16 + kg * 4) = o;
                short4 hs;
                hs.x = f2bf(o.x);
                hs.y = f2bf(o.y);
                hs.z = f2bf(o.z);
                hs.w = f2bf(o.w);
                *(short4*)(xhout + (size_t)node * HD + ct * 16 + kg * 4) = hs;
            }
        }
    }
}

// ---------------- fused MLP via bf16 MFMA, M-rep=4 (unchanged, proven) ----------------
__global__ __launch_bounds__(256) void mlp_mfma_kernel(
    const unsigned short* __restrict__ xh, const short* __restrict__ W1p,
    const float* __restrict__ L1b, const short* __restrict__ W2p,
    const float* __restrict__ L2b, const float* __restrict__ L3w,
    const float* __restrict__ L3b, float* __restrict__ score) {
    __shared__ __align__(16) char H1s[131072];
    int tid = threadIdx.x;
    int wave = tid >> 6, lane = tid & 63;
    int nl = lane & 15, kg = lane >> 4;
    int tile = blockIdx.x * 256;
    int rowbase = wave * 64;
    char* myH = H1s + wave * 32768;

    bf16x8 a1[4][4];
#pragma unroll
    for (int m = 0; m < 4; ++m) {
        int node = tile + rowbase + m * 16 + nl;
        if (node >= NN) node = NN - 1;
        const short* xr = (const short*)xh + (size_t)node * HD + kg * 8;
#pragma unroll
        for (int ks = 0; ks < 4; ++ks) a1[m][ks] = *(const bf16x8*)(xr + ks * 32);
    }

#pragma unroll
    for (int ct = 0; ct < 16; ++ct) {
        bf16x8 w[4];
#pragma unroll
        for (int ks = 0; ks < 4; ++ks)
            w[ks] = *(const bf16x8*)(W1p + (ct * 4 + ks) * 512 + lane * 8);
        f32x4 acc[4];
#pragma unroll
        for (int m = 0; m < 4; ++m) acc[m] = (f32x4){0.f, 0.f, 0.f, 0.f};
#pragma unroll
        for (int ks = 0; ks < 4; ++ks)
#pragma unroll
            for (int m = 0; m < 4; ++m)
                acc[m] = __builtin_amdgcn_mfma_f32_16x16x32_bf16(w[ks], a1[m][ks], acc[m], 0, 0, 0);
        float4 b1v = *(const float4*)(L1b + ct * 16 + kg * 4);
#pragma unroll
        for (int m = 0; m < 4; ++m) {
            short4 hs;
            hs.x = f2bf(fmaxf(acc[m][0] + b1v.x, 0.f));
            hs.y = f2bf(fmaxf(acc[m][1] + b1v.y, 0.f));
            hs.z = f2bf(fmaxf(acc[m][2] + b1v.z, 0.f));
            hs.w = f2bf(fmaxf(acc[m][3] + b1v.w, 0.f));
            int r = m * 16 + nl;
            int byte = (r * 512 + ct * 32 + kg * 8) ^ ((r & 7) << 4);
            *(short4*)(myH + byte) = hs;
        }
    }

    bf16x8 a2[4][8];
#pragma unroll
    for (int m = 0; m < 4; ++m) {
        int r = m * 16 + nl;
#pragma unroll
        for (int ks = 0; ks < 8; ++ks) {
            int byte = (r * 512 + ks * 64 + kg * 16) ^ ((r & 7) << 4);
            a2[m][ks] = *(const bf16x8*)(myH + byte);
        }
    }

    float t[4] = {0.f, 0.f, 0.f, 0.f};
#pragma unroll
    for (int ct = 0; ct < 16; ++ct) {
        bf16x8 w[8];
#pragma unroll
        for (int ks = 0; ks < 8; ++ks)
            w[ks] = *(const bf16x8*)(W2p + (ct * 8 + ks) * 512 + lane * 8);
        f32x4 acc[4];
#pragma unroll
        for (int m = 0; m < 4; ++m) acc[m] = (f32x4){0.f, 0.f, 0.f, 0.f};
#pragma unroll
        for (int ks = 0; ks < 8; ++ks)
#pragma unroll
            for (int m = 0; m < 4; ++m)
                acc[m] = __builtin_amdgcn_mfma_f32_16x16x32_bf16(w[ks], a2[m][ks], acc[m], 0, 0, 0);
        float4 b2v = *(const float4*)(L2b + ct * 16 + kg * 4);
        float4 w3v = *(const float4*)(L3w + ct * 16 + kg * 4);
#pragma unroll
        for (int m = 0; m < 4; ++m) {
            t[m] = fmaf(fmaxf(acc[m][0] + b2v.x, 0.f), w3v.x, t[m]);
            t[m] = fmaf(fmaxf(acc[m][1] + b2v.y, 0.f), w3v.y, t[m]);
            t[m] = fmaf(fmaxf(acc[m][2] + b2v.z, 0.f), w3v.z, t[m]);
            t[m] = fmaf(fmaxf(acc[m][3] + b2v.w, 0.f), w3v.w, t[m]);
        }
    }
#pragma unroll
    for (int m = 0; m < 4; ++m) {
        t[m] += __shfl_xor(t[m], 16, 64);
        t[m] += __shfl_xor(t[m], 32, 64);
    }
    if (kg == 0) {
        float b3 = L3b[0];
#pragma unroll
        for (int m = 0; m < 4; ++m) {
            int g = tile + rowbase + m * 16 + nl;
            if (g < NN) score[g] += t[m] + b3;
        }
    }
}

__global__ void final_kernel(const float* __restrict__ s1, const float* __restrict__ s2,
                             float* __restrict__ out) {
    int i = blockIdx.x * blockDim.x + threadIdx.x;
    if (i < NN) out[i] = s1[i] * s2[i];
}

extern "C" void kernel_launch(void* const* d_in, const int* in_sizes, int n_in,
                              void* d_out, int out_size, void* d_ws, size_t ws_size,
                              hipStream_t stream) {
    const int* row1 = (const int*)d_in[0];
    const int* col1 = (const int*)d_in[1];
    const float* val1 = (const float*)d_in[2];
    const int* row2 = (const int*)d_in[3];
    const int* col2 = (const int*)d_in[4];
    const float* val2 = (const float*)d_in[5];
    const float* W0 = (const float*)d_in[6];
    const float* Wg[4] = {(const float*)d_in[7], (const float*)d_in[8], (const float*)d_in[9],
                          (const float*)d_in[10]};
    const float* L1w = (const float*)d_in[11];
    const float* L1b = (const float*)d_in[12];
    const float* L2w = (const float*)d_in[13];
    const float* L2b = (const float*)d_in[14];
    const float* L3w = (const float*)d_in[15];
    const float* L3b = (const float*)d_in[16];
    float* out = (float*)d_out;

    char* ws = (char*)d_ws;
    size_t off = 0;
    auto alloc = [&](size_t bytes) {
        void* p = ws + off;
        off = (off + bytes + 255) & ~(size_t)255;
        return p;
    };
    int* rp1 = (int*)alloc((NN + 1) * 4);
    int* cols1 = (int*)alloc(EE * 4);
    float* vals1 = (float*)alloc(EE * 4);
    int* rp2 = (int*)alloc((NN + 1) * 4);
    int* cols2 = (int*)alloc(EE * 4);
    float* vals2 = (float*)alloc(EE * 4);
    int* cnt = (int*)alloc(NN * 4);
    int* cur = (int*)alloc(NN * 4);
    float* xbuf = (float*)alloc((size_t)NN * HD * 4);
    float* s1 = (float*)alloc(NN * 4);
    float* s2 = (float*)alloc(NN * 4);
    unsigned short* xh = (unsigned short*)alloc((size_t)NN * HD * 2);
    short* zh = (short*)alloc((size_t)NN * HD * 2);
    short* zl = (short*)alloc((size_t)NN * HD * 2);
    short* W1p = (short*)alloc(16 * 4 * 512 * 2);
    short* W2p = (short*)alloc(16 * 8 * 512 * 2);
    short* Wgh[4];
    short* Wgl[4];
    for (int l = 0; l < 4; ++l) {
        Wgh[l] = (short*)alloc(8 * 4 * 512 * 2);
        Wgl[l] = (short*)alloc(8 * 4 * 512 * 2);
    }

    // ---- weight prep ----
    pack_kernel<<<(16 * 4 * 64 + 255) / 256, 256, 0, stream>>>(L1w, W1p, 256, 4, 0);
    pack_kernel<<<(16 * 8 * 64 + 255) / 256, 256, 0, stream>>>(L2w, W2p, 256, 8, 0);
    for (int l = 0; l < 4; ++l) {
        pack_kernel<<<(8 * 4 * 64 + 255) / 256, 256, 0, stream>>>(Wg[l], Wgh[l], 128, 4, 0);
        pack_kernel<<<(8 * 4 * 64 + 255) / 256, 256, 0, stream>>>(Wg[l], Wgl[l], 128, 4, 1);
    }

    // ---- CSR build ----
    hipMemsetAsync(cnt, 0, NN * 4, stream);
    hipMemsetAsync(cur, 0, NN * 4, stream);
    hist_kernel<<<(EE + 255) / 256, 256, 0, stream>>>(row1, cnt);
    scan_kernel<<<1, 1024, 0, stream>>>(cnt, rp1);
    scatter_kernel<<<(EE + 255) / 256, 256, 0, stream>>>(row1, col1, val1, rp1, cur, cols1,
                                                         vals1);
    hipMemsetAsync(cnt, 0, NN * 4, stream);
    hipMemsetAsync(cur, 0, NN * 4, stream);
    hist_kernel<<<(EE + 255) / 256, 256, 0, stream>>>(row2, cnt);
    scan_kernel<<<1, 1024, 0, stream>>>(cnt, rp2);
    scatter_kernel<<<(EE + 255) / 256, 256, 0, stream>>>(row2, col2, val2, rp2, cur, cols2,
                                                         vals2);

    hipMemsetAsync(s1, 0, NN * 4, stream);
    hipMemsetAsync(s2, 0, NN * 4, stream);

    int spmm_grid = (NN * 32 + 255) / 256;
    int gemm_grid = (NN + 255) / 256;
    auto branch = [&](const int* rp, const int* cols, const float* vals, float* sc) {
        spmm_norm_kernel<<<spmm_grid, 256, 0, stream>>>(rp, cols, vals, W0, xbuf, xh);
        mlp_mfma_kernel<<<gemm_grid, 256, 0, stream>>>(xh, W1p, L1b, W2p, L2b, L3w, L3b, sc);
        for (int l = 0; l < 4; ++l) {
            spmm_raw_kernel<<<spmm_grid, 256, 0, stream>>>(rp, cols, vals, xbuf, zh, zl);
            gemm_mfma_kernel<<<gemm_grid, 256, 0, stream>>>(zh, zl, Wgh[l], Wgl[l], xbuf, xh,
                                                            l < 3 ? 1 : 0);
            mlp_mfma_kernel<<<gemm_grid, 256, 0, stream>>>(xh, W1p, L1b, W2p, L2b, L3w, L3b,
                                                           sc);
        }
    };
    branch(rp1, cols1, vals1, s1);
    branch(rp2, cols2, vals2, s2);

    final_kernel<<<(NN + 255) / 256, 256, 0, stream>>>(s1, s2, out);
}